// Round 1
// baseline (1205.715 us; speedup 1.0000x reference)
//
#include <hip/hip_runtime.h>
#include <hip/hip_bf16.h>

// EGNN layer (MC_E_GCL). f32 baseline, correctness-first.
// Inputs (f32 unless noted): h[10000,128], coord[10000,4,3], row[E]i32, col[E]i32,
// e_w1[288,128], e_b1[128], e_w2[128,128], e_b2[128], c_w1[128,128], c_b1[128],
// c_wout[128,4], n_w1[256,128], n_b1[128], n_w2[128,128], n_b2[128].
// Out: h_out[10000,128] ++ coord_out[10000,4,3] (f32).

__device__ __forceinline__ float silu_f(float x) {
    return x / (1.0f + __expf(-x));
}

// ---------------------------------------------------------------------------
// Pass 1: accumulate sum over edges of radial^2 and dist^2 per (c,f) slot.
// Layout of the 32 norm slots matches the rad feature vector:
//   slot = c*8 + f       -> radial[c][f]
//   slot = c*8 + 4 + f   -> dist[c][f]
// ---------------------------------------------------------------------------
__global__ void k_edge_norm(const float* __restrict__ coord,
                            const int* __restrict__ row,
                            const int* __restrict__ col,
                            float* __restrict__ norm_acc, int E)
{
    float p[32];
#pragma unroll
    for (int i = 0; i < 32; ++i) p[i] = 0.0f;

    for (int e = blockIdx.x * blockDim.x + threadIdx.x; e < E;
         e += gridDim.x * blockDim.x) {
        const int r = row[e], c = col[e];
        float ci[12], cj[12], d[12];
#pragma unroll
        for (int i = 0; i < 12; ++i) {
            ci[i] = coord[r * 12 + i];
            cj[i] = coord[c * 12 + i];
            d[i] = ci[i] - cj[i];
        }
#pragma unroll
        for (int a = 0; a < 4; ++a) {
#pragma unroll
            for (int b = 0; b < 4; ++b) {
                const float rad = d[a*3+0]*d[b*3+0] + d[a*3+1]*d[b*3+1] + d[a*3+2]*d[b*3+2];
                p[a*8 + b] += rad * rad;
                const float dx = ci[a*3+0] - cj[b*3+0];
                const float dy = ci[a*3+1] - cj[b*3+1];
                const float dz = ci[a*3+2] - cj[b*3+2];
                // sum of dist^2 = sum of (dx^2+dy^2+dz^2); no sqrt needed here
                p[a*8 + 4 + b] += dx*dx + dy*dy + dz*dz;
            }
        }
    }

    __shared__ float s_red[32];
    if (threadIdx.x < 32) s_red[threadIdx.x] = 0.0f;
    __syncthreads();

#pragma unroll
    for (int i = 0; i < 32; ++i) {
        float v = p[i];
        for (int off = 32; off >= 1; off >>= 1) v += __shfl_down(v, off, 64);
        if ((threadIdx.x & 63) == 0) atomicAdd(&s_red[i], v);
    }
    __syncthreads();
    if (threadIdx.x < 32) atomicAdd(&norm_acc[threadIdx.x], s_red[threadIdx.x]);
}

__global__ void k_finalize(const float* __restrict__ acc, float* __restrict__ inv)
{
    const int t = threadIdx.x;
    if (t < 32) inv[t] = 1.0f / fmaxf(sqrtf(acc[t]), 1e-12f);
}

// ---------------------------------------------------------------------------
// Pass 2: fused edge MLP + coord weights + scatter (atomics).
// 8 edges per block, 128 threads (thread = output neuron).
// ---------------------------------------------------------------------------
constexpr int EPB = 8;

__global__ __launch_bounds__(128) void k_edge_mlp(
    const float* __restrict__ h, const float* __restrict__ coord,
    const int* __restrict__ row, const int* __restrict__ col,
    const float* __restrict__ e_w1, const float* __restrict__ e_b1,
    const float* __restrict__ e_w2, const float* __restrict__ e_b2,
    const float* __restrict__ c_w1, const float* __restrict__ c_b1,
    const float* __restrict__ c_wout, const float* __restrict__ inv_norm,
    float* __restrict__ nagg, float* __restrict__ cagg, float* __restrict__ cnt,
    int E)
{
    __shared__ float s_eh[EPB][288];
    __shared__ float s_a [EPB][128];
    __shared__ float s_m [EPB][128];
    __shared__ float s_diff[EPB][12];
    __shared__ float s_w [EPB][4];
    __shared__ float s_inv[32];
    __shared__ int   s_row[EPB];

    const int t  = threadIdx.x;
    const int e0 = blockIdx.x * EPB;
    const int nE = min(EPB, E - e0);

    if (t < 32) s_inv[t] = inv_norm[t];

    // gather h rows, coord diffs, raw dist entries
    for (int e = 0; e < nE; ++e) {
        const int r = row[e0 + e];
        const int c = col[e0 + e];
        if (t == 0) s_row[e] = r;
        s_eh[e][t]       = h[(size_t)r * 128 + t];
        s_eh[e][128 + t] = h[(size_t)c * 128 + t];
        if (t < 12) s_diff[e][t] = coord[r * 12 + t] - coord[c * 12 + t];
        if (t >= 16 && t < 32) {
            const int idx = t - 16, a = idx >> 2, b = idx & 3;
            const float dx = coord[r*12 + a*3 + 0] - coord[c*12 + b*3 + 0];
            const float dy = coord[r*12 + a*3 + 1] - coord[c*12 + b*3 + 1];
            const float dz = coord[r*12 + a*3 + 2] - coord[c*12 + b*3 + 2];
            s_eh[e][256 + a*8 + 4 + b] = sqrtf(dx*dx + dy*dy + dz*dz);
        }
    }
    __syncthreads();

    // radial entries + normalization of both feature groups
    {
        const int e = t >> 4, idx = t & 15;
        if (e < nE) {
            const int a = idx >> 2, b = idx & 3;
            const float* d = s_diff[e];
            const float rad = d[a*3+0]*d[b*3+0] + d[a*3+1]*d[b*3+1] + d[a*3+2]*d[b*3+2];
            s_eh[e][256 + a*8 + b] = rad * s_inv[a*8 + b];
            s_eh[e][256 + a*8 + 4 + b] *= s_inv[a*8 + 4 + b];
        }
    }
    __syncthreads();

    // ---- edge layer 1: 288 -> 128, silu ----
    float acc[EPB];
    {
        const float b1v = e_b1[t];
#pragma unroll
        for (int e = 0; e < EPB; ++e) acc[e] = b1v;
    }
    for (int k = 0; k < 288; k += 4) {
        const float w0 = e_w1[(k+0)*128 + t];
        const float w1v = e_w1[(k+1)*128 + t];
        const float w2v = e_w1[(k+2)*128 + t];
        const float w3v = e_w1[(k+3)*128 + t];
#pragma unroll
        for (int e = 0; e < EPB; ++e) {
            const float4 v = *(const float4*)(&s_eh[e][k]);
            acc[e] = fmaf(v.x, w0,  acc[e]);
            acc[e] = fmaf(v.y, w1v, acc[e]);
            acc[e] = fmaf(v.z, w2v, acc[e]);
            acc[e] = fmaf(v.w, w3v, acc[e]);
        }
    }
#pragma unroll
    for (int e = 0; e < EPB; ++e) s_a[e][t] = silu_f(acc[e]);
    __syncthreads();

    // ---- edge layer 2: 128 -> 128, silu ; scatter m into nagg ----
    {
        const float b2v = e_b2[t];
#pragma unroll
        for (int e = 0; e < EPB; ++e) acc[e] = b2v;
    }
    for (int k = 0; k < 128; k += 4) {
        const float w0 = e_w2[(k+0)*128 + t];
        const float w1v = e_w2[(k+1)*128 + t];
        const float w2v = e_w2[(k+2)*128 + t];
        const float w3v = e_w2[(k+3)*128 + t];
#pragma unroll
        for (int e = 0; e < EPB; ++e) {
            const float4 v = *(const float4*)(&s_a[e][k]);
            acc[e] = fmaf(v.x, w0,  acc[e]);
            acc[e] = fmaf(v.y, w1v, acc[e]);
            acc[e] = fmaf(v.z, w2v, acc[e]);
            acc[e] = fmaf(v.w, w3v, acc[e]);
        }
    }
#pragma unroll
    for (int e = 0; e < EPB; ++e) {
        const float m = silu_f(acc[e]);
        s_m[e][t] = m;
        if (e < nE) atomicAdd(&nagg[(size_t)s_row[e] * 128 + t], m);
    }
    __syncthreads();

    // ---- coord layer 1: 128 -> 128, silu (into s_a, reads of s_a all done) ----
    {
        const float b3v = c_b1[t];
#pragma unroll
        for (int e = 0; e < EPB; ++e) acc[e] = b3v;
    }
    for (int k = 0; k < 128; k += 4) {
        const float w0 = c_w1[(k+0)*128 + t];
        const float w1v = c_w1[(k+1)*128 + t];
        const float w2v = c_w1[(k+2)*128 + t];
        const float w3v = c_w1[(k+3)*128 + t];
#pragma unroll
        for (int e = 0; e < EPB; ++e) {
            const float4 v = *(const float4*)(&s_m[e][k]);
            acc[e] = fmaf(v.x, w0,  acc[e]);
            acc[e] = fmaf(v.y, w1v, acc[e]);
            acc[e] = fmaf(v.z, w2v, acc[e]);
            acc[e] = fmaf(v.w, w3v, acc[e]);
        }
    }
#pragma unroll
    for (int e = 0; e < EPB; ++e) s_a[e][t] = silu_f(acc[e]);
    __syncthreads();

    // ---- coord out: 128 -> 4 per edge ----
    if (t < 32) {
        const int e = t >> 2, cc = t & 3;
        float s = 0.0f;
        for (int k = 0; k < 128; ++k) s += s_a[e][k] * c_wout[k * 4 + cc];
        s_w[e][cc] = s;
    }
    __syncthreads();

    // trans = diff * w ; scatter into cagg, count rows
    if (t < EPB * 12) {
        const int e = t / 12, i = t - e * 12, a = i / 3;
        if (e < nE) atomicAdd(&cagg[(size_t)s_row[e] * 12 + i], s_diff[e][i] * s_w[e][a]);
    }
    if (t < EPB && t < nE) atomicAdd(&cnt[s_row[t]], 1.0f);
}

// ---------------------------------------------------------------------------
// Pass 3: node MLP + residual + coord epilogue. 8 nodes per block.
// ---------------------------------------------------------------------------
constexpr int NPB = 8;

__global__ __launch_bounds__(128) void k_node(
    const float* __restrict__ h, const float* __restrict__ nagg,
    const float* __restrict__ n_w1, const float* __restrict__ n_b1,
    const float* __restrict__ n_w2, const float* __restrict__ n_b2,
    const float* __restrict__ coord, const float* __restrict__ cagg,
    const float* __restrict__ cnt,
    float* __restrict__ out_h, float* __restrict__ out_coord, int N)
{
    __shared__ float s_in[NPB][256];
    __shared__ float s_a [NPB][128];

    const int t  = threadIdx.x;
    const int n0 = blockIdx.x * NPB;
    const int nN = min(NPB, N - n0);

    for (int e = 0; e < nN; ++e) {
        s_in[e][t]       = h[(size_t)(n0 + e) * 128 + t];
        s_in[e][128 + t] = nagg[(size_t)(n0 + e) * 128 + t];
    }
    __syncthreads();

    float acc[NPB];
    {
        const float b1v = n_b1[t];
#pragma unroll
        for (int e = 0; e < NPB; ++e) acc[e] = b1v;
    }
    for (int k = 0; k < 256; k += 4) {
        const float w0 = n_w1[(k+0)*128 + t];
        const float w1v = n_w1[(k+1)*128 + t];
        const float w2v = n_w1[(k+2)*128 + t];
        const float w3v = n_w1[(k+3)*128 + t];
#pragma unroll
        for (int e = 0; e < NPB; ++e) {
            const float4 v = *(const float4*)(&s_in[e][k]);
            acc[e] = fmaf(v.x, w0,  acc[e]);
            acc[e] = fmaf(v.y, w1v, acc[e]);
            acc[e] = fmaf(v.z, w2v, acc[e]);
            acc[e] = fmaf(v.w, w3v, acc[e]);
        }
    }
#pragma unroll
    for (int e = 0; e < NPB; ++e) s_a[e][t] = silu_f(acc[e]);
    __syncthreads();

    {
        const float b2v = n_b2[t];
#pragma unroll
        for (int e = 0; e < NPB; ++e) acc[e] = b2v;
    }
    for (int k = 0; k < 128; k += 4) {
        const float w0 = n_w2[(k+0)*128 + t];
        const float w1v = n_w2[(k+1)*128 + t];
        const float w2v = n_w2[(k+2)*128 + t];
        const float w3v = n_w2[(k+3)*128 + t];
#pragma unroll
        for (int e = 0; e < NPB; ++e) {
            const float4 v = *(const float4*)(&s_a[e][k]);
            acc[e] = fmaf(v.x, w0,  acc[e]);
            acc[e] = fmaf(v.y, w1v, acc[e]);
            acc[e] = fmaf(v.z, w2v, acc[e]);
            acc[e] = fmaf(v.w, w3v, acc[e]);
        }
    }
#pragma unroll
    for (int e = 0; e < NPB; ++e) {
        if (e < nN)
            out_h[(size_t)(n0 + e) * 128 + t] = h[(size_t)(n0 + e) * 128 + t] + acc[e];
    }

    if (t < nN * 12) {
        const int e = t / 12, i = t - e * 12;
        const int n = n0 + e;
        out_coord[n * 12 + i] = coord[n * 12 + i] + cagg[n * 12 + i] / fmaxf(cnt[n], 1.0f);
    }
}

// ---------------------------------------------------------------------------
extern "C" void kernel_launch(void* const* d_in, const int* in_sizes, int n_in,
                              void* d_out, int out_size, void* d_ws, size_t ws_size,
                              hipStream_t stream)
{
    const float* h      = (const float*)d_in[0];
    const float* coord  = (const float*)d_in[1];
    const int*   row    = (const int*)d_in[2];
    const int*   col    = (const int*)d_in[3];
    const float* e_w1   = (const float*)d_in[4];
    const float* e_b1   = (const float*)d_in[5];
    const float* e_w2   = (const float*)d_in[6];
    const float* e_b2   = (const float*)d_in[7];
    const float* c_w1   = (const float*)d_in[8];
    const float* c_b1   = (const float*)d_in[9];
    const float* c_wout = (const float*)d_in[10];
    const float* n_w1   = (const float*)d_in[11];
    const float* n_b1   = (const float*)d_in[12];
    const float* n_w2   = (const float*)d_in[13];
    const float* n_b2   = (const float*)d_in[14];

    const int E = in_sizes[2];
    const int N = in_sizes[0] / 128;

    float* ws       = (float*)d_ws;
    float* norm_acc = ws;                         // 32
    float* cnt      = ws + 32;                    // N
    float* cagg     = ws + 32 + N;                // N*12
    float* nagg     = ws + 32 + N + N * 12;       // N*128
    float* inv_norm = ws + 32 + N + N * 12 + N * 128;  // 32

    const size_t zero_bytes = (size_t)(32 + N + N * 12 + N * 128) * sizeof(float);
    hipMemsetAsync(d_ws, 0, zero_bytes, stream);

    k_edge_norm<<<640, 256, 0, stream>>>(coord, row, col, norm_acc, E);
    k_finalize<<<1, 64, 0, stream>>>(norm_acc, inv_norm);
    k_edge_mlp<<<(E + EPB - 1) / EPB, 128, 0, stream>>>(
        h, coord, row, col, e_w1, e_b1, e_w2, e_b2, c_w1, c_b1, c_wout,
        inv_norm, nagg, cagg, cnt, E);

    float* out_h     = (float*)d_out;
    float* out_coord = out_h + (size_t)N * 128;
    k_node<<<(N + NPB - 1) / NPB, 128, 0, stream>>>(
        h, nagg, n_w1, n_b1, n_w2, n_b2, coord, cagg, cnt, out_h, out_coord, N);
}

// Round 2
// 668.170 us; speedup vs baseline: 1.8045x; 1.8045x over previous
//
#include <hip/hip_runtime.h>
#include <hip/hip_bf16.h>

// EGNN layer (MC_E_GCL). Round 2: edge pipeline on bf16 MFMA.
// Weights register-resident (A operand), edges staged in LDS (B operand),
// f32 accumulation, f32 atomics for node/coord scatter.

typedef __attribute__((ext_vector_type(8))) short short8;
typedef __attribute__((ext_vector_type(4))) short short4v;
typedef __attribute__((ext_vector_type(4))) float f32x4;

__device__ __forceinline__ float silu_f(float x) {
    return x / (1.0f + __expf(-x));
}
__device__ __forceinline__ float bf2f(__hip_bfloat16 b) { return __bfloat162float(b); }

// ---------------------------------------------------------------------------
// Pass 0: transpose weights to bf16 Wt[N][K] row-major in workspace.
// ---------------------------------------------------------------------------
__global__ void k_prep(const float* __restrict__ e_w1, const float* __restrict__ e_w2,
                       const float* __restrict__ c_w1,
                       __hip_bfloat16* __restrict__ w1t, __hip_bfloat16* __restrict__ w2t,
                       __hip_bfloat16* __restrict__ c1t)
{
    const int i = blockIdx.x * 256 + threadIdx.x;
    if (i < 128 * 288) {
        const int n = i / 288, k = i - n * 288;
        w1t[i] = __float2bfloat16(e_w1[k * 128 + n]);
    } else if (i < 128 * 288 + 128 * 128) {
        const int j = i - 128 * 288, n = j >> 7, k = j & 127;
        w2t[j] = __float2bfloat16(e_w2[k * 128 + n]);
    } else if (i < 128 * 288 + 2 * 128 * 128) {
        const int j = i - 128 * 288 - 128 * 128, n = j >> 7, k = j & 127;
        c1t[j] = __float2bfloat16(c_w1[k * 128 + n]);
    }
}

// ---------------------------------------------------------------------------
// Pass 1: accumulate sum over edges of radial^2 and dist^2 per (c,f) slot.
//   slot = c*8 + f -> radial[c][f] ; slot = c*8 + 4 + f -> dist[c][f]
// ---------------------------------------------------------------------------
__global__ void k_edge_norm(const float* __restrict__ coord,
                            const int* __restrict__ row,
                            const int* __restrict__ col,
                            float* __restrict__ norm_acc, int E)
{
    float p[32];
#pragma unroll
    for (int i = 0; i < 32; ++i) p[i] = 0.0f;

    for (int e = blockIdx.x * blockDim.x + threadIdx.x; e < E;
         e += gridDim.x * blockDim.x) {
        const int r = row[e], c = col[e];
        float ci[12], cj[12], d[12];
#pragma unroll
        for (int i = 0; i < 12; ++i) {
            ci[i] = coord[r * 12 + i];
            cj[i] = coord[c * 12 + i];
            d[i] = ci[i] - cj[i];
        }
#pragma unroll
        for (int a = 0; a < 4; ++a) {
#pragma unroll
            for (int b = 0; b < 4; ++b) {
                const float rad = d[a*3+0]*d[b*3+0] + d[a*3+1]*d[b*3+1] + d[a*3+2]*d[b*3+2];
                p[a*8 + b] += rad * rad;
                const float dx = ci[a*3+0] - cj[b*3+0];
                const float dy = ci[a*3+1] - cj[b*3+1];
                const float dz = ci[a*3+2] - cj[b*3+2];
                p[a*8 + 4 + b] += dx*dx + dy*dy + dz*dz;  // dist^2, sqrt not needed
            }
        }
    }

    __shared__ float s_red[32];
    if (threadIdx.x < 32) s_red[threadIdx.x] = 0.0f;
    __syncthreads();

#pragma unroll
    for (int i = 0; i < 32; ++i) {
        float v = p[i];
        for (int off = 32; off >= 1; off >>= 1) v += __shfl_down(v, off, 64);
        if ((threadIdx.x & 63) == 0) atomicAdd(&s_red[i], v);
    }
    __syncthreads();
    if (threadIdx.x < 32) atomicAdd(&norm_acc[threadIdx.x], s_red[threadIdx.x]);
}

__global__ void k_finalize(const float* __restrict__ acc, float* __restrict__ inv)
{
    const int t = threadIdx.x;
    if (t < 32) inv[t] = 1.0f / fmaxf(sqrtf(acc[t]), 1e-12f);
}

// ---------------------------------------------------------------------------
// Pass 2: fused edge pipeline on MFMA.
// 512 threads = 8 waves, wave grid (wn in 0..3) x (we in 0..1):
//   wave owns n-width 32 (2 x 16-frags), e-width 32 (2 x 16-frags).
// A operand = weights (registers), B operand = edge features (LDS).
// C layout (16x16x32): col = lane&15 (edge), row = (lane>>4)*4 + j (neuron).
// ---------------------------------------------------------------------------
constexpr int XS = 296;  // sX row stride in bf16 (288 + 8 pad -> conflict-free b128)
constexpr int BS = 136;  // sB row stride in bf16 (128 + 8 pad)

__global__ __launch_bounds__(512, 2) void k_edge_mfma(
    const float* __restrict__ h, const float* __restrict__ coord,
    const int* __restrict__ row, const int* __restrict__ col,
    const __hip_bfloat16* __restrict__ w1t, const __hip_bfloat16* __restrict__ w2t,
    const __hip_bfloat16* __restrict__ c1t,
    const float* __restrict__ e_b1, const float* __restrict__ e_b2,
    const float* __restrict__ c_b1, const float* __restrict__ c_wout,
    const float* __restrict__ inv_norm,
    float* __restrict__ nagg, float* __restrict__ cagg, float* __restrict__ cnt,
    int E, int nTiles)
{
    __shared__ __hip_bfloat16 sX[64][XS];   // eh tile [64 edges][288]
    __shared__ __hip_bfloat16 sB1[64][BS];  // layer1 out / coord-layer out
    __shared__ float s_diff[64][12];
    __shared__ float s_w[64][4];
    __shared__ float s_inv[32];
    __shared__ float s_cw[512];
    __shared__ int   s_rowv[64];
    // sB2 (layer2 out = message m) aliases sX: sX reads end before sB2 writes
    // (barrier-separated), and sB2 reads end before next tile's sX stage.
    __hip_bfloat16 (*sB2)[BS] = (__hip_bfloat16 (*)[BS])&sX[0][0];

    const int tid = threadIdx.x;
    const int wv = tid >> 6, wn = wv >> 1, we = wv & 1;
    const int lane = tid & 63, l15 = lane & 15;
    const int kq = (lane >> 4) * 8;   // k offset of this lane's 8 elements
    const int jr = (lane >> 4) * 4;   // row offset of this lane's 4 acc elems

    if (tid < 32) s_inv[tid] = inv_norm[tid];
    s_cw[tid] = c_wout[tid];  // 128*4 = 512 = blockDim

    // ---- register-resident weights + biases ----
    short8 w1f[2][9], w2f[2][4], w3f[2][4];
    float b1v[2][4], b2v[2][4], b3v[2][4];
#pragma unroll
    for (int nf = 0; nf < 2; ++nf) {
        const int nrow = wn * 32 + nf * 16 + l15;
#pragma unroll
        for (int s = 0; s < 9; ++s)
            w1f[nf][s] = *(const short8*)&w1t[nrow * 288 + s * 32 + kq];
#pragma unroll
        for (int s = 0; s < 4; ++s)
            w2f[nf][s] = *(const short8*)&w2t[nrow * 128 + s * 32 + kq];
#pragma unroll
        for (int s = 0; s < 4; ++s)
            w3f[nf][s] = *(const short8*)&c1t[nrow * 128 + s * 32 + kq];
        const int nb = wn * 32 + nf * 16 + jr;
#pragma unroll
        for (int j = 0; j < 4; ++j) {
            b1v[nf][j] = e_b1[nb + j];
            b2v[nf][j] = e_b2[nb + j];
            b3v[nf][j] = c_b1[nb + j];
        }
    }
    __syncthreads();

    for (int tile = blockIdx.x; tile < nTiles; tile += gridDim.x) {
        const int e0 = tile * 64;
        const int nE = min(64, E - e0);

        // ---- stage: gather h[row], h[col] -> bf16 LDS; 8 threads/edge ----
        {
            const int e = tid >> 3, p = tid & 7;
            if (e < nE) {
                const int r = row[e0 + e], c = col[e0 + e];
                if (p == 0) s_rowv[e] = r;
                const float* hr = h + (size_t)r * 128 + p * 16;
                const float* hc = h + (size_t)c * 128 + p * 16;
                union { short8 s; __hip_bfloat16 b[8]; } u;
#pragma unroll
                for (int half = 0; half < 2; ++half) {
                    const float* src = half ? hc : hr;
                    const int base = half * 128 + p * 16;
#pragma unroll
                    for (int i = 0; i < 2; ++i) {
                        const float4 v0 = *(const float4*)(src + i * 8);
                        const float4 v1 = *(const float4*)(src + i * 8 + 4);
                        u.b[0] = __float2bfloat16(v0.x); u.b[1] = __float2bfloat16(v0.y);
                        u.b[2] = __float2bfloat16(v0.z); u.b[3] = __float2bfloat16(v0.w);
                        u.b[4] = __float2bfloat16(v1.x); u.b[5] = __float2bfloat16(v1.y);
                        u.b[6] = __float2bfloat16(v1.z); u.b[7] = __float2bfloat16(v1.w);
                        *(short8*)&sX[e][base + i * 8] = u.s;
                    }
                }
            }
        }
        // rad features, one thread per edge
        if (tid < 64 && tid < nE) {
            const int e = tid;
            const int r = row[e0 + e], c = col[e0 + e];
            float ci[12], cj[12], d[12];
#pragma unroll
            for (int i = 0; i < 3; ++i) {
                *(float4*)&ci[i * 4] = *(const float4*)&coord[r * 12 + i * 4];
                *(float4*)&cj[i * 4] = *(const float4*)&coord[c * 12 + i * 4];
            }
#pragma unroll
            for (int i = 0; i < 12; ++i) { d[i] = ci[i] - cj[i]; s_diff[e][i] = d[i]; }
#pragma unroll
            for (int a = 0; a < 4; ++a)
#pragma unroll
                for (int b = 0; b < 4; ++b) {
                    const float rad = d[a*3]*d[b*3] + d[a*3+1]*d[b*3+1] + d[a*3+2]*d[b*3+2];
                    const float dx = ci[a*3]   - cj[b*3];
                    const float dy = ci[a*3+1] - cj[b*3+1];
                    const float dz = ci[a*3+2] - cj[b*3+2];
                    const float ds = sqrtf(dx*dx + dy*dy + dz*dz);
                    sX[e][256 + a*8 + b]     = __float2bfloat16(rad * s_inv[a*8 + b]);
                    sX[e][256 + a*8 + 4 + b] = __float2bfloat16(ds  * s_inv[a*8 + 4 + b]);
                }
        }
        __syncthreads();

        const int eb0 = we * 32 + l15;
        f32x4 acc[2][2];

        // ---- layer 1: eh[64,288] @ W1 -> silu -> sB1 ----
#pragma unroll
        for (int nf = 0; nf < 2; ++nf)
#pragma unroll
            for (int ef = 0; ef < 2; ++ef)
#pragma unroll
                for (int j = 0; j < 4; ++j) acc[nf][ef][j] = b1v[nf][j];
#pragma unroll
        for (int s = 0; s < 9; ++s) {
            const short8 bf0 = *(const short8*)&sX[eb0][s * 32 + kq];
            const short8 bf1 = *(const short8*)&sX[eb0 + 16][s * 32 + kq];
            acc[0][0] = __builtin_amdgcn_mfma_f32_16x16x32_bf16(w1f[0][s], bf0, acc[0][0], 0, 0, 0);
            acc[0][1] = __builtin_amdgcn_mfma_f32_16x16x32_bf16(w1f[0][s], bf1, acc[0][1], 0, 0, 0);
            acc[1][0] = __builtin_amdgcn_mfma_f32_16x16x32_bf16(w1f[1][s], bf0, acc[1][0], 0, 0, 0);
            acc[1][1] = __builtin_amdgcn_mfma_f32_16x16x32_bf16(w1f[1][s], bf1, acc[1][1], 0, 0, 0);
        }
#pragma unroll
        for (int nf = 0; nf < 2; ++nf)
#pragma unroll
            for (int ef = 0; ef < 2; ++ef) {
                const int e = we * 32 + ef * 16 + l15, nb = wn * 32 + nf * 16 + jr;
                union { short4v s; __hip_bfloat16 b[4]; } u;
#pragma unroll
                for (int j = 0; j < 4; ++j) u.b[j] = __float2bfloat16(silu_f(acc[nf][ef][j]));
                *(short4v*)&sB1[e][nb] = u.s;
            }
        __syncthreads();

        // ---- layer 2: sB1 @ W2 -> silu = m ; atomics to nagg ; write sB2 ----
#pragma unroll
        for (int nf = 0; nf < 2; ++nf)
#pragma unroll
            for (int ef = 0; ef < 2; ++ef)
#pragma unroll
                for (int j = 0; j < 4; ++j) acc[nf][ef][j] = b2v[nf][j];
#pragma unroll
        for (int s = 0; s < 4; ++s) {
            const short8 bf0 = *(const short8*)&sB1[eb0][s * 32 + kq];
            const short8 bf1 = *(const short8*)&sB1[eb0 + 16][s * 32 + kq];
            acc[0][0] = __builtin_amdgcn_mfma_f32_16x16x32_bf16(w2f[0][s], bf0, acc[0][0], 0, 0, 0);
            acc[0][1] = __builtin_amdgcn_mfma_f32_16x16x32_bf16(w2f[0][s], bf1, acc[0][1], 0, 0, 0);
            acc[1][0] = __builtin_amdgcn_mfma_f32_16x16x32_bf16(w2f[1][s], bf0, acc[1][0], 0, 0, 0);
            acc[1][1] = __builtin_amdgcn_mfma_f32_16x16x32_bf16(w2f[1][s], bf1, acc[1][1], 0, 0, 0);
        }
#pragma unroll
        for (int nf = 0; nf < 2; ++nf)
#pragma unroll
            for (int ef = 0; ef < 2; ++ef) {
                const int e = we * 32 + ef * 16 + l15, nb = wn * 32 + nf * 16 + jr;
                float mv[4];
#pragma unroll
                for (int j = 0; j < 4; ++j) mv[j] = silu_f(acc[nf][ef][j]);
                if (e < nE) {
                    float* np = &nagg[(size_t)s_rowv[e] * 128 + nb];
                    atomicAdd(np + 0, mv[0]); atomicAdd(np + 1, mv[1]);
                    atomicAdd(np + 2, mv[2]); atomicAdd(np + 3, mv[3]);
                }
                union { short4v s; __hip_bfloat16 b[4]; } u;
#pragma unroll
                for (int j = 0; j < 4; ++j) u.b[j] = __float2bfloat16(mv[j]);
                *(short4v*)&sB2[e][nb] = u.s;
            }
        __syncthreads();

        // ---- layer 3 (coord MLP): sB2 @ c_w1 -> silu -> sB1 ----
#pragma unroll
        for (int nf = 0; nf < 2; ++nf)
#pragma unroll
            for (int ef = 0; ef < 2; ++ef)
#pragma unroll
                for (int j = 0; j < 4; ++j) acc[nf][ef][j] = b3v[nf][j];
#pragma unroll
        for (int s = 0; s < 4; ++s) {
            const short8 bf0 = *(const short8*)&sB2[eb0][s * 32 + kq];
            const short8 bf1 = *(const short8*)&sB2[eb0 + 16][s * 32 + kq];
            acc[0][0] = __builtin_amdgcn_mfma_f32_16x16x32_bf16(w3f[0][s], bf0, acc[0][0], 0, 0, 0);
            acc[0][1] = __builtin_amdgcn_mfma_f32_16x16x32_bf16(w3f[0][s], bf1, acc[0][1], 0, 0, 0);
            acc[1][0] = __builtin_amdgcn_mfma_f32_16x16x32_bf16(w3f[1][s], bf0, acc[1][0], 0, 0, 0);
            acc[1][1] = __builtin_amdgcn_mfma_f32_16x16x32_bf16(w3f[1][s], bf1, acc[1][1], 0, 0, 0);
        }
#pragma unroll
        for (int nf = 0; nf < 2; ++nf)
#pragma unroll
            for (int ef = 0; ef < 2; ++ef) {
                const int e = we * 32 + ef * 16 + l15, nb = wn * 32 + nf * 16 + jr;
                union { short4v s; __hip_bfloat16 b[4]; } u;
#pragma unroll
                for (int j = 0; j < 4; ++j) u.b[j] = __float2bfloat16(silu_f(acc[nf][ef][j]));
                *(short4v*)&sB1[e][nb] = u.s;
            }
        __syncthreads();

        // ---- coord out: [64,128] @ c_wout[128,4] ----
        if (tid < 256) {
            const int e = tid >> 2, cc = tid & 3;
            float s = 0.0f;
#pragma unroll 8
            for (int k = 0; k < 128; ++k) s += bf2f(sB1[e][k]) * s_cw[k * 4 + cc];
            s_w[e][cc] = s;
        }
        __syncthreads();

        // ---- trans scatter ----
        for (int i = tid; i < nE * 12; i += 512) {
            const int e = i / 12, dd = i - e * 12;
            atomicAdd(&cagg[(size_t)s_rowv[e] * 12 + dd], s_diff[e][dd] * s_w[e][dd / 3]);
        }
        if (tid < nE) atomicAdd(&cnt[s_rowv[tid]], 1.0f);
        __syncthreads();
    }
}

// ---------------------------------------------------------------------------
// Pass 3: node MLP + residual + coord epilogue. 8 nodes per block. (f32)
// ---------------------------------------------------------------------------
constexpr int NPB = 8;

__global__ __launch_bounds__(128) void k_node(
    const float* __restrict__ h, const float* __restrict__ nagg,
    const float* __restrict__ n_w1, const float* __restrict__ n_b1,
    const float* __restrict__ n_w2, const float* __restrict__ n_b2,
    const float* __restrict__ coord, const float* __restrict__ cagg,
    const float* __restrict__ cnt,
    float* __restrict__ out_h, float* __restrict__ out_coord, int N)
{
    __shared__ float s_in[NPB][256];
    __shared__ float s_a [NPB][128];

    const int t  = threadIdx.x;
    const int n0 = blockIdx.x * NPB;
    const int nN = min(NPB, N - n0);

    for (int e = 0; e < nN; ++e) {
        s_in[e][t]       = h[(size_t)(n0 + e) * 128 + t];
        s_in[e][128 + t] = nagg[(size_t)(n0 + e) * 128 + t];
    }
    __syncthreads();

    float acc[NPB];
    {
        const float b1v = n_b1[t];
#pragma unroll
        for (int e = 0; e < NPB; ++e) acc[e] = b1v;
    }
    for (int k = 0; k < 256; k += 4) {
        const float w0 = n_w1[(k+0)*128 + t];
        const float w1v = n_w1[(k+1)*128 + t];
        const float w2v = n_w1[(k+2)*128 + t];
        const float w3v = n_w1[(k+3)*128 + t];
#pragma unroll
        for (int e = 0; e < NPB; ++e) {
            const float4 v = *(const float4*)(&s_in[e][k]);
            acc[e] = fmaf(v.x, w0,  acc[e]);
            acc[e] = fmaf(v.y, w1v, acc[e]);
            acc[e] = fmaf(v.z, w2v, acc[e]);
            acc[e] = fmaf(v.w, w3v, acc[e]);
        }
    }
#pragma unroll
    for (int e = 0; e < NPB; ++e) s_a[e][t] = silu_f(acc[e]);
    __syncthreads();

    {
        const float b2v = n_b2[t];
#pragma unroll
        for (int e = 0; e < NPB; ++e) acc[e] = b2v;
    }
    for (int k = 0; k < 128; k += 4) {
        const float w0 = n_w2[(k+0)*128 + t];
        const float w1v = n_w2[(k+1)*128 + t];
        const float w2v = n_w2[(k+2)*128 + t];
        const float w3v = n_w2[(k+3)*128 + t];
#pragma unroll
        for (int e = 0; e < NPB; ++e) {
            const float4 v = *(const float4*)(&s_a[e][k]);
            acc[e] = fmaf(v.x, w0,  acc[e]);
            acc[e] = fmaf(v.y, w1v, acc[e]);
            acc[e] = fmaf(v.z, w2v, acc[e]);
            acc[e] = fmaf(v.w, w3v, acc[e]);
        }
    }
#pragma unroll
    for (int e = 0; e < NPB; ++e) {
        if (e < nN)
            out_h[(size_t)(n0 + e) * 128 + t] = h[(size_t)(n0 + e) * 128 + t] + acc[e];
    }

    if (t < nN * 12) {
        const int e = t / 12, i = t - e * 12;
        const int n = n0 + e;
        out_coord[n * 12 + i] = coord[n * 12 + i] + cagg[n * 12 + i] / fmaxf(cnt[n], 1.0f);
    }
}

// ---------------------------------------------------------------------------
extern "C" void kernel_launch(void* const* d_in, const int* in_sizes, int n_in,
                              void* d_out, int out_size, void* d_ws, size_t ws_size,
                              hipStream_t stream)
{
    const float* h      = (const float*)d_in[0];
    const float* coord  = (const float*)d_in[1];
    const int*   row    = (const int*)d_in[2];
    const int*   col    = (const int*)d_in[3];
    const float* e_w1   = (const float*)d_in[4];
    const float* e_b1   = (const float*)d_in[5];
    const float* e_w2   = (const float*)d_in[6];
    const float* e_b2   = (const float*)d_in[7];
    const float* c_w1   = (const float*)d_in[8];
    const float* c_b1   = (const float*)d_in[9];
    const float* c_wout = (const float*)d_in[10];
    const float* n_w1   = (const float*)d_in[11];
    const float* n_b1   = (const float*)d_in[12];
    const float* n_w2   = (const float*)d_in[13];
    const float* n_b2   = (const float*)d_in[14];

    const int E = in_sizes[2];
    const int N = in_sizes[0] / 128;

    float* ws       = (float*)d_ws;
    float* norm_acc = ws;                              // 32
    float* cnt      = ws + 32;                         // N
    float* cagg     = cnt + N;                         // N*12
    float* nagg     = cagg + (size_t)N * 12;           // N*128
    float* inv_norm = nagg + (size_t)N * 128;          // 32
    __hip_bfloat16* w1t = (__hip_bfloat16*)(inv_norm + 32);  // 128*288 (16B aligned)
    __hip_bfloat16* w2t = w1t + 128 * 288;                   // 128*128
    __hip_bfloat16* c1t = w2t + 128 * 128;                   // 128*128

    const size_t zero_bytes = (size_t)(32 + N + N * 12 + N * 128) * sizeof(float);
    hipMemsetAsync(d_ws, 0, zero_bytes, stream);

    k_prep<<<272, 256, 0, stream>>>(e_w1, e_w2, c_w1, w1t, w2t, c1t);
    k_edge_norm<<<640, 256, 0, stream>>>(coord, row, col, norm_acc, E);
    k_finalize<<<1, 64, 0, stream>>>(norm_acc, inv_norm);

    const int nTiles = (E + 63) / 64;
    k_edge_mfma<<<1024, 512, 0, stream>>>(
        h, coord, row, col, w1t, w2t, c1t, e_b1, e_b2, c_b1, c_wout,
        inv_norm, nagg, cagg, cnt, E, nTiles);

    float* out_h     = (float*)d_out;
    float* out_coord = out_h + (size_t)N * 128;
    k_node<<<(N + NPB - 1) / NPB, 128, 0, stream>>>(
        h, nagg, n_w1, n_b1, n_w2, n_b2, coord, cagg, cnt, out_h, out_coord, N);
}

// Round 3
// 365.918 us; speedup vs baseline: 3.2950x; 1.8260x over previous
//
#include <hip/hip_runtime.h>
#include <hip/hip_bf16.h>

// EGNN layer (MC_E_GCL). Round 3: CSR-sorted edges, segmented-sum scatter
// (atomics reduced ~20x), bf16 MFMA edge pipeline with register weights.

typedef __attribute__((ext_vector_type(8))) short short8;
typedef __attribute__((ext_vector_type(4))) short short4v;
typedef __attribute__((ext_vector_type(4))) float f32x4;

__device__ __forceinline__ float silu_f(float x) {
    return x / (1.0f + __expf(-x));
}
__device__ __forceinline__ float bf2f(__hip_bfloat16 b) { return __bfloat162float(b); }

// ---------------------------------------------------------------------------
// Pass 0: transpose weights to bf16 Wt[N][K] row-major in workspace.
// ---------------------------------------------------------------------------
__global__ void k_prep(const float* __restrict__ e_w1, const float* __restrict__ e_w2,
                       const float* __restrict__ c_w1,
                       __hip_bfloat16* __restrict__ w1t, __hip_bfloat16* __restrict__ w2t,
                       __hip_bfloat16* __restrict__ c1t)
{
    const int i = blockIdx.x * 256 + threadIdx.x;
    if (i < 128 * 288) {
        const int n = i / 288, k = i - n * 288;
        w1t[i] = __float2bfloat16(e_w1[k * 128 + n]);
    } else if (i < 128 * 288 + 128 * 128) {
        const int j = i - 128 * 288, n = j >> 7, k = j & 127;
        w2t[j] = __float2bfloat16(e_w2[k * 128 + n]);
    } else if (i < 128 * 288 + 2 * 128 * 128) {
        const int j = i - 128 * 288 - 128 * 128, n = j >> 7, k = j & 127;
        c1t[j] = __float2bfloat16(c_w1[k * 128 + n]);
    }
}

// ---------------------------------------------------------------------------
// CSR build: histogram -> scan -> scatter (counting sort by row).
// ---------------------------------------------------------------------------
__global__ void k_hist(const int* __restrict__ row, int* __restrict__ deg, int E)
{
    const int e = blockIdx.x * 256 + threadIdx.x;
    if (e < E) atomicAdd(&deg[row[e]], 1);
}

__global__ void k_scan(const int* __restrict__ deg, int* __restrict__ row_ptr, int N)
{
    __shared__ int s[256];
    const int t = threadIdx.x;
    const int chunk = (N + 255) / 256;
    const int lo = t * chunk, hi = min(lo + chunk, N);
    int sum = 0;
    for (int i = lo; i < hi; ++i) sum += deg[i];
    s[t] = sum;
    __syncthreads();
    for (int off = 1; off < 256; off <<= 1) {
        int v = (t >= off) ? s[t - off] : 0;
        __syncthreads();
        s[t] += v;
        __syncthreads();
    }
    int running = s[t] - sum;  // exclusive prefix of this chunk
    for (int i = lo; i < hi; ++i) { row_ptr[i] = running; running += deg[i]; }
    if (hi == N) row_ptr[N] = running + (s[255] - s[t]);  // = total E
}

__global__ void k_scatter(const int* __restrict__ row, const int* __restrict__ row_ptr,
                          int* __restrict__ cur, int* __restrict__ csr, int E)
{
    const int e = blockIdx.x * 256 + threadIdx.x;
    if (e < E) {
        const int r = row[e];
        const int idx = row_ptr[r] + atomicAdd(&cur[r], 1);
        csr[idx] = e;
    }
}

// ---------------------------------------------------------------------------
// Pass 1: accumulate sum over edges of radial^2 and dist^2 per (c,f) slot.
//   slot = c*8 + f -> radial[c][f] ; slot = c*8 + 4 + f -> dist[c][f]
// ---------------------------------------------------------------------------
__global__ void k_edge_norm(const float* __restrict__ coord,
                            const int* __restrict__ row,
                            const int* __restrict__ col,
                            float* __restrict__ norm_acc, int E)
{
    float p[32];
#pragma unroll
    for (int i = 0; i < 32; ++i) p[i] = 0.0f;

    for (int e = blockIdx.x * blockDim.x + threadIdx.x; e < E;
         e += gridDim.x * blockDim.x) {
        const int r = row[e], c = col[e];
        float ci[12], cj[12], d[12];
#pragma unroll
        for (int i = 0; i < 12; ++i) {
            ci[i] = coord[r * 12 + i];
            cj[i] = coord[c * 12 + i];
            d[i] = ci[i] - cj[i];
        }
#pragma unroll
        for (int a = 0; a < 4; ++a) {
#pragma unroll
            for (int b = 0; b < 4; ++b) {
                const float rad = d[a*3+0]*d[b*3+0] + d[a*3+1]*d[b*3+1] + d[a*3+2]*d[b*3+2];
                p[a*8 + b] += rad * rad;
                const float dx = ci[a*3+0] - cj[b*3+0];
                const float dy = ci[a*3+1] - cj[b*3+1];
                const float dz = ci[a*3+2] - cj[b*3+2];
                p[a*8 + 4 + b] += dx*dx + dy*dy + dz*dz;  // dist^2
            }
        }
    }

    __shared__ float s_red[32];
    if (threadIdx.x < 32) s_red[threadIdx.x] = 0.0f;
    __syncthreads();

#pragma unroll
    for (int i = 0; i < 32; ++i) {
        float v = p[i];
        for (int off = 32; off >= 1; off >>= 1) v += __shfl_down(v, off, 64);
        if ((threadIdx.x & 63) == 0) atomicAdd(&s_red[i], v);
    }
    __syncthreads();
    if (threadIdx.x < 32) atomicAdd(&norm_acc[threadIdx.x], s_red[threadIdx.x]);
}

__global__ void k_finalize(const float* __restrict__ acc, float* __restrict__ inv)
{
    const int t = threadIdx.x;
    if (t < 32) inv[t] = 1.0f / fmaxf(sqrtf(acc[t]), 1e-12f);
}

// ---------------------------------------------------------------------------
// Pass 2: fused edge pipeline on MFMA over CSR-sorted edges.
// 512 threads = 8 waves, wave grid (wn 0..3) x (we 0..1).
// Segmented (per distinct row in tile) sums -> few atomics.
// ---------------------------------------------------------------------------
constexpr int XS = 296;  // sX row stride (bf16)
constexpr int BS = 136;  // sB row stride (bf16)

__global__ __launch_bounds__(512, 2) void k_edge_mfma(
    const float* __restrict__ h, const float* __restrict__ coord,
    const int* __restrict__ row, const int* __restrict__ col,
    const int* __restrict__ csr,
    const __hip_bfloat16* __restrict__ w1t, const __hip_bfloat16* __restrict__ w2t,
    const __hip_bfloat16* __restrict__ c1t,
    const float* __restrict__ e_b1, const float* __restrict__ e_b2,
    const float* __restrict__ c_b1, const float* __restrict__ c_wout,
    const float* __restrict__ inv_norm,
    float* __restrict__ nagg, float* __restrict__ cagg,
    int E, int nTiles)
{
    __shared__ __hip_bfloat16 sX[64][XS];
    __shared__ __hip_bfloat16 sB1[64][BS];
    __shared__ float s_diff[64][12];
    __shared__ float s_w[64][4];
    __shared__ float s_inv[32];
    __shared__ float s_cw[512];
    __shared__ int   s_rowv[64];
    __shared__ int   s_segstart[65];
    __shared__ int   s_segrow[64];
    __shared__ int   s_nseg;
    __hip_bfloat16 (*sB2)[BS] = (__hip_bfloat16 (*)[BS])&sX[0][0];  // aliases sX

    const int tid = threadIdx.x;
    const int wv = tid >> 6, wn = wv >> 1, we = wv & 1;
    const int lane = tid & 63, l15 = lane & 15;
    const int kq = (lane >> 4) * 8;
    const int jr = (lane >> 4) * 4;

    if (tid < 32) s_inv[tid] = inv_norm[tid];
    s_cw[tid] = c_wout[tid];

    short8 w1f[2][9], w2f[2][4], w3f[2][4];
    float b1v[2][4], b2v[2][4], b3v[2][4];
#pragma unroll
    for (int nf = 0; nf < 2; ++nf) {
        const int nrow = wn * 32 + nf * 16 + l15;
#pragma unroll
        for (int s = 0; s < 9; ++s)
            w1f[nf][s] = *(const short8*)&w1t[nrow * 288 + s * 32 + kq];
#pragma unroll
        for (int s = 0; s < 4; ++s)
            w2f[nf][s] = *(const short8*)&w2t[nrow * 128 + s * 32 + kq];
#pragma unroll
        for (int s = 0; s < 4; ++s)
            w3f[nf][s] = *(const short8*)&c1t[nrow * 128 + s * 32 + kq];
        const int nb = wn * 32 + nf * 16 + jr;
#pragma unroll
        for (int j = 0; j < 4; ++j) {
            b1v[nf][j] = e_b1[nb + j];
            b2v[nf][j] = e_b2[nb + j];
            b3v[nf][j] = c_b1[nb + j];
        }
    }
    __syncthreads();

    for (int tile = blockIdx.x; tile < nTiles; tile += gridDim.x) {
        const int e0 = tile * 64;
        const int nE = min(64, E - e0);

        // ---- stage eh tile (sorted order) ----
        {
            const int e = tid >> 3, p = tid & 7;
            if (e < nE) {
                const int eid = csr[e0 + e];
                const int r = row[eid], c = col[eid];
                if (p == 0) s_rowv[e] = r;
                union { short8 s; __hip_bfloat16 b[8]; } u;
#pragma unroll
                for (int half = 0; half < 2; ++half) {
                    const float* src = (half ? (h + (size_t)c * 128) : (h + (size_t)r * 128)) + p * 16;
                    const int base = half * 128 + p * 16;
#pragma unroll
                    for (int i = 0; i < 2; ++i) {
                        const float4 v0 = *(const float4*)(src + i * 8);
                        const float4 v1 = *(const float4*)(src + i * 8 + 4);
                        u.b[0] = __float2bfloat16(v0.x); u.b[1] = __float2bfloat16(v0.y);
                        u.b[2] = __float2bfloat16(v0.z); u.b[3] = __float2bfloat16(v0.w);
                        u.b[4] = __float2bfloat16(v1.x); u.b[5] = __float2bfloat16(v1.y);
                        u.b[6] = __float2bfloat16(v1.z); u.b[7] = __float2bfloat16(v1.w);
                        *(short8*)&sX[e][base + i * 8] = u.s;
                    }
                }
            }
        }
        if (tid < 64 && tid < nE) {
            const int e = tid;
            const int eid = csr[e0 + e];
            const int r = row[eid], c = col[eid];
            float ci[12], cj[12], d[12];
#pragma unroll
            for (int i = 0; i < 3; ++i) {
                *(float4*)&ci[i * 4] = *(const float4*)&coord[r * 12 + i * 4];
                *(float4*)&cj[i * 4] = *(const float4*)&coord[c * 12 + i * 4];
            }
#pragma unroll
            for (int i = 0; i < 12; ++i) { d[i] = ci[i] - cj[i]; s_diff[e][i] = d[i]; }
#pragma unroll
            for (int a = 0; a < 4; ++a)
#pragma unroll
                for (int b = 0; b < 4; ++b) {
                    const float rad = d[a*3]*d[b*3] + d[a*3+1]*d[b*3+1] + d[a*3+2]*d[b*3+2];
                    const float dx = ci[a*3]   - cj[b*3];
                    const float dy = ci[a*3+1] - cj[b*3+1];
                    const float dz = ci[a*3+2] - cj[b*3+2];
                    const float ds = sqrtf(dx*dx + dy*dy + dz*dz);
                    sX[e][256 + a*8 + b]     = __float2bfloat16(rad * s_inv[a*8 + b]);
                    sX[e][256 + a*8 + 4 + b] = __float2bfloat16(ds  * s_inv[a*8 + 4 + b]);
                }
        }
        __syncthreads();

        // ---- wave 0: build row segments (rows are sorted within tile) ----
        if (tid < 64) {
            const int i = tid;
            const bool valid = i < nE;
            const int r = valid ? s_rowv[i] : -1;
            const bool flag = valid && (i == 0 || r != s_rowv[i - 1]);
            const unsigned long long mask = __ballot(flag);
            if (flag) {
                const int s = (i == 0) ? 0 : __popcll(mask & ((1ull << i) - 1));
                s_segstart[s] = i;
                s_segrow[s] = r;
            }
            if (i == 0) {
                const int nseg = __popcll(mask);
                s_nseg = nseg;
                s_segstart[nseg] = nE;
            }
        }

        const int eb0 = we * 32 + l15;
        f32x4 acc[2][2];

        // ---- layer 1: eh @ W1 -> silu -> sB1 ----
#pragma unroll
        for (int nf = 0; nf < 2; ++nf)
#pragma unroll
            for (int ef = 0; ef < 2; ++ef)
#pragma unroll
                for (int j = 0; j < 4; ++j) acc[nf][ef][j] = b1v[nf][j];
#pragma unroll
        for (int s = 0; s < 9; ++s) {
            const short8 bf0 = *(const short8*)&sX[eb0][s * 32 + kq];
            const short8 bf1 = *(const short8*)&sX[eb0 + 16][s * 32 + kq];
            acc[0][0] = __builtin_amdgcn_mfma_f32_16x16x32_bf16(w1f[0][s], bf0, acc[0][0], 0, 0, 0);
            acc[0][1] = __builtin_amdgcn_mfma_f32_16x16x32_bf16(w1f[0][s], bf1, acc[0][1], 0, 0, 0);
            acc[1][0] = __builtin_amdgcn_mfma_f32_16x16x32_bf16(w1f[1][s], bf0, acc[1][0], 0, 0, 0);
            acc[1][1] = __builtin_amdgcn_mfma_f32_16x16x32_bf16(w1f[1][s], bf1, acc[1][1], 0, 0, 0);
        }
#pragma unroll
        for (int nf = 0; nf < 2; ++nf)
#pragma unroll
            for (int ef = 0; ef < 2; ++ef) {
                const int e = we * 32 + ef * 16 + l15, nb = wn * 32 + nf * 16 + jr;
                union { short4v s; __hip_bfloat16 b[4]; } u;
#pragma unroll
                for (int j = 0; j < 4; ++j) u.b[j] = __float2bfloat16(silu_f(acc[nf][ef][j]));
                *(short4v*)&sB1[e][nb] = u.s;
            }
        __syncthreads();

        // ---- layer 2: sB1 @ W2 -> silu = m -> sB2 (bf16) ----
#pragma unroll
        for (int nf = 0; nf < 2; ++nf)
#pragma unroll
            for (int ef = 0; ef < 2; ++ef)
#pragma unroll
                for (int j = 0; j < 4; ++j) acc[nf][ef][j] = b2v[nf][j];
#pragma unroll
        for (int s = 0; s < 4; ++s) {
            const short8 bf0 = *(const short8*)&sB1[eb0][s * 32 + kq];
            const short8 bf1 = *(const short8*)&sB1[eb0 + 16][s * 32 + kq];
            acc[0][0] = __builtin_amdgcn_mfma_f32_16x16x32_bf16(w2f[0][s], bf0, acc[0][0], 0, 0, 0);
            acc[0][1] = __builtin_amdgcn_mfma_f32_16x16x32_bf16(w2f[0][s], bf1, acc[0][1], 0, 0, 0);
            acc[1][0] = __builtin_amdgcn_mfma_f32_16x16x32_bf16(w2f[1][s], bf0, acc[1][0], 0, 0, 0);
            acc[1][1] = __builtin_amdgcn_mfma_f32_16x16x32_bf16(w2f[1][s], bf1, acc[1][1], 0, 0, 0);
        }
#pragma unroll
        for (int nf = 0; nf < 2; ++nf)
#pragma unroll
            for (int ef = 0; ef < 2; ++ef) {
                const int e = we * 32 + ef * 16 + l15, nb = wn * 32 + nf * 16 + jr;
                union { short4v s; __hip_bfloat16 b[4]; } u;
#pragma unroll
                for (int j = 0; j < 4; ++j) u.b[j] = __float2bfloat16(silu_f(acc[nf][ef][j]));
                *(short4v*)&sB2[e][nb] = u.s;
            }
        __syncthreads();

        // ---- layer 3 (coord MLP) + segmented nagg reduction (both read sB2) ----
#pragma unroll
        for (int nf = 0; nf < 2; ++nf)
#pragma unroll
            for (int ef = 0; ef < 2; ++ef)
#pragma unroll
                for (int j = 0; j < 4; ++j) acc[nf][ef][j] = b3v[nf][j];
#pragma unroll
        for (int s = 0; s < 4; ++s) {
            const short8 bf0 = *(const short8*)&sB2[eb0][s * 32 + kq];
            const short8 bf1 = *(const short8*)&sB2[eb0 + 16][s * 32 + kq];
            acc[0][0] = __builtin_amdgcn_mfma_f32_16x16x32_bf16(w3f[0][s], bf0, acc[0][0], 0, 0, 0);
            acc[0][1] = __builtin_amdgcn_mfma_f32_16x16x32_bf16(w3f[0][s], bf1, acc[0][1], 0, 0, 0);
            acc[1][0] = __builtin_amdgcn_mfma_f32_16x16x32_bf16(w3f[1][s], bf0, acc[1][0], 0, 0, 0);
            acc[1][1] = __builtin_amdgcn_mfma_f32_16x16x32_bf16(w3f[1][s], bf1, acc[1][1], 0, 0, 0);
        }
        {
            const int nseg = s_nseg;
            const int c = tid & 127;
            for (int s = tid >> 7; s < nseg; s += 4) {
                const int b = s_segstart[s], en = s_segstart[s + 1];
                float sum = 0.0f;
                for (int e = b; e < en; ++e) sum += bf2f(sB2[e][c]);
                atomicAdd(&nagg[(size_t)s_segrow[s] * 128 + c], sum);
            }
        }
#pragma unroll
        for (int nf = 0; nf < 2; ++nf)
#pragma unroll
            for (int ef = 0; ef < 2; ++ef) {
                const int e = we * 32 + ef * 16 + l15, nb = wn * 32 + nf * 16 + jr;
                union { short4v s; __hip_bfloat16 b[4]; } u;
#pragma unroll
                for (int j = 0; j < 4; ++j) u.b[j] = __float2bfloat16(silu_f(acc[nf][ef][j]));
                *(short4v*)&sB1[e][nb] = u.s;
            }
        __syncthreads();

        // ---- coord out: [64,128] @ c_wout[128,4] ----
        if (tid < 256) {
            const int e = tid >> 2, cc = tid & 3;
            float s = 0.0f;
#pragma unroll 8
            for (int k = 0; k < 128; ++k) s += bf2f(sB1[e][k]) * s_cw[k * 4 + cc];
            s_w[e][cc] = s;
        }
        __syncthreads();

        // ---- segmented cagg reduction ----
        {
            const int nseg = s_nseg;
            for (int i = tid; i < nseg * 12; i += 512) {
                const int s = i / 12, dd = i - 12 * s;
                const int b = s_segstart[s], en = s_segstart[s + 1];
                float sum = 0.0f;
                for (int e = b; e < en; ++e) sum += s_diff[e][dd] * s_w[e][dd / 3];
                atomicAdd(&cagg[(size_t)s_segrow[s] * 12 + dd], sum);
            }
        }
        __syncthreads();
    }
}

// ---------------------------------------------------------------------------
// Pass 3: node MLP + residual + coord epilogue. 8 nodes per block. (f32)
// ---------------------------------------------------------------------------
constexpr int NPB = 8;

__global__ __launch_bounds__(128) void k_node(
    const float* __restrict__ h, const float* __restrict__ nagg,
    const float* __restrict__ n_w1, const float* __restrict__ n_b1,
    const float* __restrict__ n_w2, const float* __restrict__ n_b2,
    const float* __restrict__ coord, const float* __restrict__ cagg,
    const int* __restrict__ row_ptr,
    float* __restrict__ out_h, float* __restrict__ out_coord, int N)
{
    __shared__ float s_in[NPB][256];
    __shared__ float s_a [NPB][128];

    const int t  = threadIdx.x;
    const int n0 = blockIdx.x * NPB;
    const int nN = min(NPB, N - n0);

    for (int e = 0; e < nN; ++e) {
        s_in[e][t]       = h[(size_t)(n0 + e) * 128 + t];
        s_in[e][128 + t] = nagg[(size_t)(n0 + e) * 128 + t];
    }
    __syncthreads();

    float acc[NPB];
    {
        const float b1v = n_b1[t];
#pragma unroll
        for (int e = 0; e < NPB; ++e) acc[e] = b1v;
    }
    for (int k = 0; k < 256; k += 4) {
        const float w0 = n_w1[(k+0)*128 + t];
        const float w1v = n_w1[(k+1)*128 + t];
        const float w2v = n_w1[(k+2)*128 + t];
        const float w3v = n_w1[(k+3)*128 + t];
#pragma unroll
        for (int e = 0; e < NPB; ++e) {
            const float4 v = *(const float4*)(&s_in[e][k]);
            acc[e] = fmaf(v.x, w0,  acc[e]);
            acc[e] = fmaf(v.y, w1v, acc[e]);
            acc[e] = fmaf(v.z, w2v, acc[e]);
            acc[e] = fmaf(v.w, w3v, acc[e]);
        }
    }
#pragma unroll
    for (int e = 0; e < NPB; ++e) s_a[e][t] = silu_f(acc[e]);
    __syncthreads();

    {
        const float b2v = n_b2[t];
#pragma unroll
        for (int e = 0; e < NPB; ++e) acc[e] = b2v;
    }
    for (int k = 0; k < 128; k += 4) {
        const float w0 = n_w2[(k+0)*128 + t];
        const float w1v = n_w2[(k+1)*128 + t];
        const float w2v = n_w2[(k+2)*128 + t];
        const float w3v = n_w2[(k+3)*128 + t];
#pragma unroll
        for (int e = 0; e < NPB; ++e) {
            const float4 v = *(const float4*)(&s_a[e][k]);
            acc[e] = fmaf(v.x, w0,  acc[e]);
            acc[e] = fmaf(v.y, w1v, acc[e]);
            acc[e] = fmaf(v.z, w2v, acc[e]);
            acc[e] = fmaf(v.w, w3v, acc[e]);
        }
    }
#pragma unroll
    for (int e = 0; e < NPB; ++e) {
        if (e < nN)
            out_h[(size_t)(n0 + e) * 128 + t] = h[(size_t)(n0 + e) * 128 + t] + acc[e];
    }

    if (t < nN * 12) {
        const int e = t / 12, i = t - e * 12;
        const int n = n0 + e;
        const float cntv = (float)(row_ptr[n + 1] - row_ptr[n]);
        out_coord[n * 12 + i] = coord[n * 12 + i] + cagg[n * 12 + i] / fmaxf(cntv, 1.0f);
    }
}

// ---------------------------------------------------------------------------
extern "C" void kernel_launch(void* const* d_in, const int* in_sizes, int n_in,
                              void* d_out, int out_size, void* d_ws, size_t ws_size,
                              hipStream_t stream)
{
    const float* h      = (const float*)d_in[0];
    const float* coord  = (const float*)d_in[1];
    const int*   row    = (const int*)d_in[2];
    const int*   col    = (const int*)d_in[3];
    const float* e_w1   = (const float*)d_in[4];
    const float* e_b1   = (const float*)d_in[5];
    const float* e_w2   = (const float*)d_in[6];
    const float* e_b2   = (const float*)d_in[7];
    const float* c_w1   = (const float*)d_in[8];
    const float* c_b1   = (const float*)d_in[9];
    const float* c_wout = (const float*)d_in[10];
    const float* n_w1   = (const float*)d_in[11];
    const float* n_b1   = (const float*)d_in[12];
    const float* n_w2   = (const float*)d_in[13];
    const float* n_b2   = (const float*)d_in[14];

    const int E = in_sizes[2];
    const int N = in_sizes[0] / 128;

    // workspace layout (zeroed region first)
    float* ws       = (float*)d_ws;
    float* norm_acc = ws;                               // 32
    int*   deg      = (int*)(ws + 32);                  // N
    int*   cur      = deg + N;                          // N
    float* nagg     = (float*)(cur + N);                // N*128
    float* cagg     = nagg + (size_t)N * 128;           // N*12
    // non-zeroed:
    int*   row_ptr  = (int*)(cagg + (size_t)N * 12);    // N+1 (rounded to N+4)
    int*   csr      = row_ptr + ((N + 4) & ~3);         // E
    float* inv_norm = (float*)(csr + E);                // 32
    __hip_bfloat16* w1t = (__hip_bfloat16*)(inv_norm + 32);  // 128*288
    __hip_bfloat16* w2t = w1t + 128 * 288;
    __hip_bfloat16* c1t = w2t + 128 * 128;

    const size_t zero_bytes = (size_t)(32 + 2 * N + N * 128 + N * 12) * sizeof(float);
    hipMemsetAsync(d_ws, 0, zero_bytes, stream);

    k_prep<<<272, 256, 0, stream>>>(e_w1, e_w2, c_w1, w1t, w2t, c1t);
    k_hist<<<(E + 255) / 256, 256, 0, stream>>>(row, deg, E);
    k_edge_norm<<<640, 256, 0, stream>>>(coord, row, col, norm_acc, E);
    k_scan<<<1, 256, 0, stream>>>(deg, row_ptr, N);
    k_scatter<<<(E + 255) / 256, 256, 0, stream>>>(row, row_ptr, cur, csr, E);
    k_finalize<<<1, 64, 0, stream>>>(norm_acc, inv_norm);

    const int nTiles = (E + 63) / 64;
    k_edge_mfma<<<512, 512, 0, stream>>>(
        h, coord, row, col, csr, w1t, w2t, c1t, e_b1, e_b2, c_b1, c_wout,
        inv_norm, nagg, cagg, E, nTiles);

    float* out_h     = (float*)d_out;
    float* out_coord = out_h + (size_t)N * 128;
    k_node<<<(N + NPB - 1) / NPB, 128, 0, stream>>>(
        h, nagg, n_w1, n_b1, n_w2, n_b2, coord, cagg, row_ptr, out_h, out_coord, N);
}

// Round 6
// 276.601 us; speedup vs baseline: 4.3590x; 1.3229x over previous
//
#include <hip/hip_runtime.h>
#include <hip/hip_bf16.h>

// EGNN layer (MC_E_GCL). Round 6: round-4 structure with the phase-A staging
// bug fixed (short8 = 8 bf16, so each 16-elem slot needs TWO short8 copies).
// hb (bf16 h table) hosted in d_out (dead until k_node overwrites it).

typedef __attribute__((ext_vector_type(8))) short short8;
typedef __attribute__((ext_vector_type(4))) short short4v;
typedef __attribute__((ext_vector_type(4))) float f32x4;

__device__ __forceinline__ float silu_f(float x) {
    return x / (1.0f + __expf(-x));
}
__device__ __forceinline__ float bf2f(__hip_bfloat16 b) { return __bfloat162float(b); }

// ---------------------------------------------------------------------------
// Pass 0a: transpose weights to bf16 Wt[N][K]; padded cwt[16][136] (c_wout^T).
// ---------------------------------------------------------------------------
__global__ void k_prep(const float* __restrict__ e_w1, const float* __restrict__ e_w2,
                       const float* __restrict__ c_w1, const float* __restrict__ c_wout,
                       __hip_bfloat16* __restrict__ w1t, __hip_bfloat16* __restrict__ w2t,
                       __hip_bfloat16* __restrict__ c1t, __hip_bfloat16* __restrict__ cwt)
{
    const int i = blockIdx.x * 256 + threadIdx.x;
    if (i < 36864) {                       // 128x288
        const int n = i / 288, k = i - n * 288;
        w1t[i] = __float2bfloat16(e_w1[k * 128 + n]);
    } else if (i < 53248) {                // 128x128
        const int j = i - 36864, n = j >> 7, k = j & 127;
        w2t[j] = __float2bfloat16(e_w2[k * 128 + n]);
    } else if (i < 69632) {                // 128x128
        const int j = i - 53248, n = j >> 7, k = j & 127;
        c1t[j] = __float2bfloat16(c_w1[k * 128 + n]);
    } else if (i < 71808) {                // 16x136 padded c_wout^T
        const int j = i - 69632, n = j / 136, k = j - n * 136;
        cwt[j] = (n < 4 && k < 128) ? __float2bfloat16(c_wout[k * 4 + n])
                                    : __float2bfloat16(0.0f);
    }
}

// Pass 0b: h -> bf16 table (2.5 MB, hosted in d_out; fully rewritten per call).
__global__ void k_prep_h(const float* __restrict__ h, __hip_bfloat16* __restrict__ hb,
                         int total)
{
    const int i = blockIdx.x * 256 + threadIdx.x;
    if (i * 2 < total) {
        const float2 v = *(const float2*)&h[i * 2];
        union { ushort2 u; __hip_bfloat16 b[2]; } p;
        p.b[0] = __float2bfloat16(v.x);
        p.b[1] = __float2bfloat16(v.y);
        *(ushort2*)&hb[i * 2] = p.u;
    }
}

// ---------------------------------------------------------------------------
// CSR build: histogram -> scan -> scatter.
// ---------------------------------------------------------------------------
__global__ void k_hist(const int* __restrict__ row, int* __restrict__ deg, int E)
{
    const int e = blockIdx.x * 256 + threadIdx.x;
    if (e < E) atomicAdd(&deg[row[e]], 1);
}

__global__ void k_scan(const int* __restrict__ deg, int* __restrict__ row_ptr, int N)
{
    __shared__ int s[256];
    const int t = threadIdx.x;
    const int chunk = (N + 255) / 256;
    const int lo = t * chunk, hi = min(lo + chunk, N);
    int sum = 0;
    for (int i = lo; i < hi; ++i) sum += deg[i];
    s[t] = sum;
    __syncthreads();
    for (int off = 1; off < 256; off <<= 1) {
        int v = (t >= off) ? s[t - off] : 0;
        __syncthreads();
        s[t] += v;
        __syncthreads();
    }
    int running = s[t] - sum;
    for (int i = lo; i < hi; ++i) { row_ptr[i] = running; running += deg[i]; }
    if (hi == N) row_ptr[N] = running + (s[255] - s[t]);
}

__global__ void k_scatter(const int* __restrict__ row, const int* __restrict__ row_ptr,
                          int* __restrict__ cur, int* __restrict__ csr, int E)
{
    const int e = blockIdx.x * 256 + threadIdx.x;
    if (e < E) {
        const int r = row[e];
        const int idx = row_ptr[r] + atomicAdd(&cur[r], 1);
        csr[idx] = e;
    }
}

// ---------------------------------------------------------------------------
// Pass 1: global norms (sum radial^2, sum dist^2 per (c,f) slot).
// ---------------------------------------------------------------------------
__global__ void k_edge_norm(const float* __restrict__ coord,
                            const int* __restrict__ row,
                            const int* __restrict__ col,
                            float* __restrict__ norm_acc, int E)
{
    float p[32];
#pragma unroll
    for (int i = 0; i < 32; ++i) p[i] = 0.0f;

    for (int e = blockIdx.x * blockDim.x + threadIdx.x; e < E;
         e += gridDim.x * blockDim.x) {
        const int r = row[e], c = col[e];
        float ci[12], cj[12], d[12];
#pragma unroll
        for (int i = 0; i < 12; ++i) {
            ci[i] = coord[r * 12 + i];
            cj[i] = coord[c * 12 + i];
            d[i] = ci[i] - cj[i];
        }
#pragma unroll
        for (int a = 0; a < 4; ++a) {
#pragma unroll
            for (int b = 0; b < 4; ++b) {
                const float rad = d[a*3+0]*d[b*3+0] + d[a*3+1]*d[b*3+1] + d[a*3+2]*d[b*3+2];
                p[a*8 + b] += rad * rad;
                const float dx = ci[a*3+0] - cj[b*3+0];
                const float dy = ci[a*3+1] - cj[b*3+1];
                const float dz = ci[a*3+2] - cj[b*3+2];
                p[a*8 + 4 + b] += dx*dx + dy*dy + dz*dz;
            }
        }
    }

    __shared__ float s_red[32];
    if (threadIdx.x < 32) s_red[threadIdx.x] = 0.0f;
    __syncthreads();
#pragma unroll
    for (int i = 0; i < 32; ++i) {
        float v = p[i];
        for (int off = 32; off >= 1; off >>= 1) v += __shfl_down(v, off, 64);
        if ((threadIdx.x & 63) == 0) atomicAdd(&s_red[i], v);
    }
    __syncthreads();
    if (threadIdx.x < 32) atomicAdd(&norm_acc[threadIdx.x], s_red[threadIdx.x]);
}

__global__ void k_finalize(const float* __restrict__ acc, float* __restrict__ inv)
{
    const int t = threadIdx.x;
    if (t < 32) inv[t] = 1.0f / fmaxf(sqrtf(acc[t]), 1e-12f);
}

// ---------------------------------------------------------------------------
// Pass 2: fused edge pipeline, 8 waves = 8 n-groups of 16, each over 64 edges.
// ---------------------------------------------------------------------------
constexpr int XS = 296;
constexpr int BS = 136;

__global__ __launch_bounds__(512, 4) void k_edge_mfma(
    const __hip_bfloat16* __restrict__ hb, const float* __restrict__ coord,
    const int* __restrict__ row, const int* __restrict__ col,
    const int* __restrict__ csr,
    const __hip_bfloat16* __restrict__ w1t, const __hip_bfloat16* __restrict__ w2t,
    const __hip_bfloat16* __restrict__ c1t, const __hip_bfloat16* __restrict__ cwt,
    const float* __restrict__ e_b1, const float* __restrict__ e_b2,
    const float* __restrict__ c_b1, const float* __restrict__ inv_norm,
    float* __restrict__ nagg, float* __restrict__ cagg,
    int E, int nTiles)
{
    __shared__ __hip_bfloat16 sX[64][XS];
    __shared__ __hip_bfloat16 sB1[64][BS];
    __shared__ __hip_bfloat16 s_cwt[16][BS];
    __shared__ float s_diff[64][12];
    __shared__ float s_w[64][4];
    __shared__ float s_inv[32];
    __shared__ int   s_rowv[64];
    __shared__ int   s_segstart[65];
    __shared__ int   s_segrow[64];
    __shared__ int   s_nseg;
    __hip_bfloat16 (*sB2)[BS] = (__hip_bfloat16 (*)[BS])&sX[0][0];   // alias sX
    float (*s_ci)[12] = (float (*)[12])&sB1[0][0];                    // alias sB1
    float (*s_cj)[12] = s_ci + 64;

    const int tid = threadIdx.x;
    const int wv = tid >> 6;           // n-group 0..7
    const int lane = tid & 63, l15 = lane & 15;
    const int kq = (lane >> 4) * 8;
    const int jr = (lane >> 4) * 4;
    const int nb = wv * 16 + jr;

    if (tid < 32) s_inv[tid] = inv_norm[tid];
    if (tid < 272) ((short8*)&s_cwt[0][0])[tid] = ((const short8*)cwt)[tid];

    // register-resident weights (68 VGPR) + biases
    short8 w1f[9], w2f[4], w3f[4];
    float b1v[4], b2v[4], b3v[4];
    {
        const int nrow = wv * 16 + l15;
#pragma unroll
        for (int s = 0; s < 9; ++s) w1f[s] = *(const short8*)&w1t[nrow * 288 + s * 32 + kq];
#pragma unroll
        for (int s = 0; s < 4; ++s) w2f[s] = *(const short8*)&w2t[nrow * 128 + s * 32 + kq];
#pragma unroll
        for (int s = 0; s < 4; ++s) w3f[s] = *(const short8*)&c1t[nrow * 128 + s * 32 + kq];
#pragma unroll
        for (int j = 0; j < 4; ++j) {
            b1v[j] = e_b1[nb + j]; b2v[j] = e_b2[nb + j]; b3v[j] = c_b1[nb + j];
        }
    }
    __syncthreads();

    for (int tile = blockIdx.x; tile < nTiles; tile += gridDim.x) {
        const int e0 = tile * 64;
        const int nE = min(64, E - e0);

        // ---- phase A: copy bf16 h rows (16 bf16 = TWO short8 per slot!) ----
        {
            const int e = tid >> 3, p = tid & 7;
            if (e < nE) {
                const int eid = csr[e0 + e];
                const int r = row[eid], c = col[eid];
                const __hip_bfloat16* hr = &hb[(size_t)r * 128 + p * 16];
                const __hip_bfloat16* hc = &hb[(size_t)c * 128 + p * 16];
                *(short8*)&sX[e][p * 16]           = *(const short8*)(hr);
                *(short8*)&sX[e][p * 16 + 8]       = *(const short8*)(hr + 8);
                *(short8*)&sX[e][128 + p * 16]     = *(const short8*)(hc);
                *(short8*)&sX[e][128 + p * 16 + 8] = *(const short8*)(hc + 8);
                if (p == 0) {
                    s_rowv[e] = r;
                    *(float4*)&s_ci[e][0] = *(const float4*)&coord[r * 12];
                    *(float4*)&s_ci[e][4] = *(const float4*)&coord[r * 12 + 4];
                    *(float4*)&s_ci[e][8] = *(const float4*)&coord[r * 12 + 8];
                } else if (p == 1) {
                    *(float4*)&s_cj[e][0] = *(const float4*)&coord[c * 12];
                    *(float4*)&s_cj[e][4] = *(const float4*)&coord[c * 12 + 4];
                    *(float4*)&s_cj[e][8] = *(const float4*)&coord[c * 12 + 8];
                }
            }
        }
        __syncthreads();

        // ---- phase B: rad features, 2 (a,b) pairs per thread ----
        {
            const int e = tid >> 3, pp = (tid & 7) * 2;
            if (e < nE) {
#pragma unroll
                for (int t2 = 0; t2 < 2; ++t2) {
                    const int pr = pp + t2, a = pr >> 2, b = pr & 3;
                    const float cax = s_ci[e][a*3], cay = s_ci[e][a*3+1], caz = s_ci[e][a*3+2];
                    const float jax = s_cj[e][a*3], jay = s_cj[e][a*3+1], jaz = s_cj[e][a*3+2];
                    const float cbx = s_ci[e][b*3], cby = s_ci[e][b*3+1], cbz = s_ci[e][b*3+2];
                    const float jbx = s_cj[e][b*3], jby = s_cj[e][b*3+1], jbz = s_cj[e][b*3+2];
                    const float dax = cax - jax, day = cay - jay, daz = caz - jaz;
                    const float dbx = cbx - jbx, dby = cby - jby, dbz = cbz - jbz;
                    const float rad = dax*dbx + day*dby + daz*dbz;
                    const float dx = cax - jbx, dy = cay - jby, dz = caz - jbz;
                    const float ds = sqrtf(dx*dx + dy*dy + dz*dz);
                    sX[e][256 + a*8 + b]     = __float2bfloat16(rad * s_inv[a*8 + b]);
                    sX[e][256 + a*8 + 4 + b] = __float2bfloat16(ds  * s_inv[a*8 + 4 + b]);
                    if (a == b) {
                        s_diff[e][a*3] = dax; s_diff[e][a*3+1] = day; s_diff[e][a*3+2] = daz;
                    }
                }
            }
        }
        // ---- wave 0: segment build over sorted rows ----
        if (tid < 64) {
            const int i = tid;
            const bool valid = i < nE;
            const int r = valid ? s_rowv[i] : -1;
            const bool flag = valid && (i == 0 || r != s_rowv[i - 1]);
            const unsigned long long mask = __ballot(flag);
            if (flag) {
                const int s = (i == 0) ? 0 : __popcll(mask & ((1ull << i) - 1));
                s_segstart[s] = i;
                s_segrow[s] = r;
            }
            if (i == 0) {
                const int nseg = __popcll(mask);
                s_nseg = nseg;
                s_segstart[nseg] = nE;
            }
        }
        __syncthreads();

        f32x4 acc[4];

        // ---- layer 1: eh @ W1 -> silu -> sB1 ----
#pragma unroll
        for (int ef = 0; ef < 4; ++ef) {
            acc[ef][0] = b1v[0]; acc[ef][1] = b1v[1]; acc[ef][2] = b1v[2]; acc[ef][3] = b1v[3];
        }
#pragma unroll
        for (int s = 0; s < 9; ++s) {
            const short8 a = w1f[s];
#pragma unroll
            for (int ef = 0; ef < 4; ++ef) {
                const short8 b = *(const short8*)&sX[ef * 16 + l15][s * 32 + kq];
                acc[ef] = __builtin_amdgcn_mfma_f32_16x16x32_bf16(a, b, acc[ef], 0, 0, 0);
            }
        }
#pragma unroll
        for (int ef = 0; ef < 4; ++ef) {
            union { short4v s; __hip_bfloat16 b[4]; } u;
#pragma unroll
            for (int j = 0; j < 4; ++j) u.b[j] = __float2bfloat16(silu_f(acc[ef][j]));
            *(short4v*)&sB1[ef * 16 + l15][nb] = u.s;
        }
        __syncthreads();

        // ---- layer 2: sB1 @ W2 -> silu = m -> sB2 ----
#pragma unroll
        for (int ef = 0; ef < 4; ++ef) {
            acc[ef][0] = b2v[0]; acc[ef][1] = b2v[1]; acc[ef][2] = b2v[2]; acc[ef][3] = b2v[3];
        }
#pragma unroll
        for (int s = 0; s < 4; ++s) {
            const short8 a = w2f[s];
#pragma unroll
            for (int ef = 0; ef < 4; ++ef) {
                const short8 b = *(const short8*)&sB1[ef * 16 + l15][s * 32 + kq];
                acc[ef] = __builtin_amdgcn_mfma_f32_16x16x32_bf16(a, b, acc[ef], 0, 0, 0);
            }
        }
        __syncthreads();   // all prior sX reads complete before sB2 (alias) writes
#pragma unroll
        for (int ef = 0; ef < 4; ++ef) {
            union { short4v s; __hip_bfloat16 b[4]; } u;
#pragma unroll
            for (int j = 0; j < 4; ++j) u.b[j] = __float2bfloat16(silu_f(acc[ef][j]));
            *(short4v*)&sB2[ef * 16 + l15][nb] = u.s;
        }
        __syncthreads();

        // ---- layer 3: m @ c_w1 -> silu -> sB1 ; nagg segmented sum (reads sB2) ----
#pragma unroll
        for (int ef = 0; ef < 4; ++ef) {
            acc[ef][0] = b3v[0]; acc[ef][1] = b3v[1]; acc[ef][2] = b3v[2]; acc[ef][3] = b3v[3];
        }
#pragma unroll
        for (int s = 0; s < 4; ++s) {
            const short8 a = w3f[s];
#pragma unroll
            for (int ef = 0; ef < 4; ++ef) {
                const short8 b = *(const short8*)&sB2[ef * 16 + l15][s * 32 + kq];
                acc[ef] = __builtin_amdgcn_mfma_f32_16x16x32_bf16(a, b, acc[ef], 0, 0, 0);
            }
        }
        {
            const int nseg = s_nseg;
            const int c = tid & 127;
            for (int s = tid >> 7; s < nseg; s += 4) {
                const int b = s_segstart[s], en = s_segstart[s + 1];
                float sum = 0.0f;
                for (int e = b; e < en; ++e) sum += bf2f(sB2[e][c]);
                atomicAdd(&nagg[(size_t)s_segrow[s] * 128 + c], sum);
            }
        }
#pragma unroll
        for (int ef = 0; ef < 4; ++ef) {
            union { short4v s; __hip_bfloat16 b[4]; } u;
#pragma unroll
            for (int j = 0; j < 4; ++j) u.b[j] = __float2bfloat16(silu_f(acc[ef][j]));
            *(short4v*)&sB1[ef * 16 + l15][nb] = u.s;
        }
        __syncthreads();

        // ---- coord-out via MFMA: s_w[64][4] = sB1 @ c_wout (padded 16 rows) ----
        if (wv < 4) {
            f32x4 cacc = {0.0f, 0.0f, 0.0f, 0.0f};
#pragma unroll
            for (int s = 0; s < 4; ++s) {
                const short8 a = *(const short8*)&s_cwt[l15][s * 32 + kq];
                const short8 b = *(const short8*)&sB1[wv * 16 + l15][s * 32 + kq];
                cacc = __builtin_amdgcn_mfma_f32_16x16x32_bf16(a, b, cacc, 0, 0, 0);
            }
            if (lane < 16) {
#pragma unroll
                for (int j = 0; j < 4; ++j) s_w[wv * 16 + l15][j] = cacc[j];
            }
        }
        __syncthreads();

        // ---- segmented cagg reduction ----
        {
            const int nseg = s_nseg;
            for (int i = tid; i < nseg * 12; i += 512) {
                const int s = i / 12, dd = i - 12 * s;
                const int b = s_segstart[s], en = s_segstart[s + 1];
                float sum = 0.0f;
                for (int e = b; e < en; ++e) sum += s_diff[e][dd] * s_w[e][dd / 3];
                atomicAdd(&cagg[(size_t)s_segrow[s] * 12 + dd], sum);
            }
        }
        __syncthreads();
    }
}

// ---------------------------------------------------------------------------
// Pass 3: node MLP + residual + coord epilogue. 8 nodes per block. (f32)
// ---------------------------------------------------------------------------
constexpr int NPB = 8;

__global__ __launch_bounds__(128) void k_node(
    const float* __restrict__ h, const float* __restrict__ nagg,
    const float* __restrict__ n_w1, const float* __restrict__ n_b1,
    const float* __restrict__ n_w2, const float* __restrict__ n_b2,
    const float* __restrict__ coord, const float* __restrict__ cagg,
    const int* __restrict__ row_ptr,
    float* __restrict__ out_h, float* __restrict__ out_coord, int N)
{
    __shared__ float s_in[NPB][256];
    __shared__ float s_a [NPB][128];

    const int t  = threadIdx.x;
    const int n0 = blockIdx.x * NPB;
    const int nN = min(NPB, N - n0);

    for (int e = 0; e < nN; ++e) {
        s_in[e][t]       = h[(size_t)(n0 + e) * 128 + t];
        s_in[e][128 + t] = nagg[(size_t)(n0 + e) * 128 + t];
    }
    __syncthreads();

    float acc[NPB];
    {
        const float b1v = n_b1[t];
#pragma unroll
        for (int e = 0; e < NPB; ++e) acc[e] = b1v;
    }
    for (int k = 0; k < 256; k += 4) {
        const float w0 = n_w1[(k+0)*128 + t];
        const float w1v = n_w1[(k+1)*128 + t];
        const float w2v = n_w1[(k+2)*128 + t];
        const float w3v = n_w1[(k+3)*128 + t];
#pragma unroll
        for (int e = 0; e < NPB; ++e) {
            const float4 v = *(const float4*)(&s_in[e][k]);
            acc[e] = fmaf(v.x, w0,  acc[e]);
            acc[e] = fmaf(v.y, w1v, acc[e]);
            acc[e] = fmaf(v.z, w2v, acc[e]);
            acc[e] = fmaf(v.w, w3v, acc[e]);
        }
    }
#pragma unroll
    for (int e = 0; e < NPB; ++e) s_a[e][t] = silu_f(acc[e]);
    __syncthreads();

    {
        const float b2v = n_b2[t];
#pragma unroll
        for (int e = 0; e < NPB; ++e) acc[e] = b2v;
    }
    for (int k = 0; k < 128; k += 4) {
        const float w0 = n_w2[(k+0)*128 + t];
        const float w1v = n_w2[(k+1)*128 + t];
        const float w2v = n_w2[(k+2)*128 + t];
        const float w3v = n_w2[(k+3)*128 + t];
#pragma unroll
        for (int e = 0; e < NPB; ++e) {
            const float4 v = *(const float4*)(&s_a[e][k]);
            acc[e] = fmaf(v.x, w0,  acc[e]);
            acc[e] = fmaf(v.y, w1v, acc[e]);
            acc[e] = fmaf(v.z, w2v, acc[e]);
            acc[e] = fmaf(v.w, w3v, acc[e]);
        }
    }
#pragma unroll
    for (int e = 0; e < NPB; ++e) {
        if (e < nN)
            out_h[(size_t)(n0 + e) * 128 + t] = h[(size_t)(n0 + e) * 128 + t] + acc[e];
    }

    if (t < nN * 12) {
        const int e = t / 12, i = t - e * 12;
        const int n = n0 + e;
        const float cntv = (float)(row_ptr[n + 1] - row_ptr[n]);
        out_coord[n * 12 + i] = coord[n * 12 + i] + cagg[n * 12 + i] / fmaxf(cntv, 1.0f);
    }
}

// ---------------------------------------------------------------------------
extern "C" void kernel_launch(void* const* d_in, const int* in_sizes, int n_in,
                              void* d_out, int out_size, void* d_ws, size_t ws_size,
                              hipStream_t stream)
{
    const float* h      = (const float*)d_in[0];
    const float* coord  = (const float*)d_in[1];
    const int*   row    = (const int*)d_in[2];
    const int*   col    = (const int*)d_in[3];
    const float* e_w1   = (const float*)d_in[4];
    const float* e_b1   = (const float*)d_in[5];
    const float* e_w2   = (const float*)d_in[6];
    const float* e_b2   = (const float*)d_in[7];
    const float* c_w1   = (const float*)d_in[8];
    const float* c_b1   = (const float*)d_in[9];
    const float* c_wout = (const float*)d_in[10];
    const float* n_w1   = (const float*)d_in[11];
    const float* n_b1   = (const float*)d_in[12];
    const float* n_w2   = (const float*)d_in[13];
    const float* n_b2   = (const float*)d_in[14];

    const int E = in_sizes[2];
    const int N = in_sizes[0] / 128;

    // workspace layout (zeroed region first) — same footprint as round 3
    float* ws       = (float*)d_ws;
    float* norm_acc = ws;                               // 32
    int*   deg      = (int*)(ws + 32);                  // N
    int*   cur      = deg + N;                          // N
    float* nagg     = (float*)(cur + N);                // N*128
    float* cagg     = nagg + (size_t)N * 128;           // N*12
    // non-zeroed:
    int*   row_ptr  = (int*)(cagg + (size_t)N * 12);    // N+1 (rounded)
    int*   csr      = row_ptr + ((N + 4) & ~3);         // E
    float* inv_norm = (float*)(csr + E);                // 32
    __hip_bfloat16* w1t = (__hip_bfloat16*)(inv_norm + 32);  // 36864
    __hip_bfloat16* w2t = w1t + 36864;                       // 16384
    __hip_bfloat16* c1t = w2t + 16384;                       // 16384
    __hip_bfloat16* cwt = c1t + 16384;                       // 2176

    // bf16 h table lives in d_out (dead until k_node; fully rewritten per call)
    __hip_bfloat16* hb = (__hip_bfloat16*)d_out;             // N*128 bf16 = 2.56 MB

    const size_t zero_bytes = (size_t)(32 + 2 * N + N * 128 + N * 12) * sizeof(float);
    hipMemsetAsync(d_ws, 0, zero_bytes, stream);

    k_prep<<<281, 256, 0, stream>>>(e_w1, e_w2, c_w1, c_wout, w1t, w2t, c1t, cwt);
    k_prep_h<<<(N * 64 + 255) / 256, 256, 0, stream>>>(h, hb, N * 128);
    k_hist<<<(E + 255) / 256, 256, 0, stream>>>(row, deg, E);
    k_edge_norm<<<640, 256, 0, stream>>>(coord, row, col, norm_acc, E);
    k_scan<<<1, 256, 0, stream>>>(deg, row_ptr, N);
    k_scatter<<<(E + 255) / 256, 256, 0, stream>>>(row, row_ptr, cur, csr, E);
    k_finalize<<<1, 64, 0, stream>>>(norm_acc, inv_norm);

    const int nTiles = (E + 63) / 64;
    k_edge_mfma<<<512, 512, 0, stream>>>(
        hb, coord, row, col, csr, w1t, w2t, c1t, cwt,
        e_b1, e_b2, c_b1, inv_norm, nagg, cagg, E, nTiles);

    float* out_h     = (float*)d_out;
    float* out_coord = out_h + (size_t)N * 128;
    k_node<<<(N + NPB - 1) / NPB, 128, 0, stream>>>(
        h, nagg, n_w1, n_b1, n_w2, n_b2, coord, cagg, row_ptr, out_h, out_coord, N);
}